// Round 19
// baseline (4236.573 us; speedup 1.0000x reference)
//
#include <hip/hip_runtime.h>
#include <stdint.h>

#define K_DIM 4096
#define N_DIM 11008
#define M_DIM 8192

constexpr int BM = 128, BN = 128, BK = 64;
constexpr int NT  = K_DIM / BK;    // 64
constexpr int NZW = N_DIM / 8;     // 1376
constexpr int NXT = N_DIM / BN;    // 86
constexpr int MXT = M_DIM / BM;    // 64
constexpr int NWG = NXT * MXT;     // 5504 = 8 * 688
constexpr int TILE_ELEMS = BM * BK;  // 8192 f16 = 16 KiB per K-tile

typedef _Float16 f16x2  __attribute__((ext_vector_type(2)));
typedef _Float16 f16x8  __attribute__((ext_vector_type(8)));
typedef float    f32x4  __attribute__((ext_vector_type(4)));
typedef float    f32x16 __attribute__((ext_vector_type(16)));
union H8 { f16x8 v; f16x2 p[4]; };

// word w holds nibbles for k-offsets 0..7; output k-order (0,4,1,5,2,6,3,7).
// Legal for MFMA because A octets carry the SAME permutation (via prep):
// element j of A and B refer to the same true k, so the 8-k sum is complete.
__device__ __forceinline__ f16x8 dq_word(uint32_t w, f16x2 ss, f16x2 zz) {
    H8 r;
    uint32_t t0 = ( w        & 0x000F000Fu) | 0x64006400u;
    uint32_t t1 = ((w >> 4)  & 0x000F000Fu) | 0x64006400u;
    uint32_t t2 = ((w >> 8)  & 0x000F000Fu) | 0x64006400u;
    uint32_t t3 = ((w >> 12) & 0x000F000Fu) | 0x64006400u;
    r.p[0] = (__builtin_bit_cast(f16x2, t0) - zz) * ss;
    r.p[1] = (__builtin_bit_cast(f16x2, t1) - zz) * ss;
    r.p[2] = (__builtin_bit_cast(f16x2, t2) - zz) * ss;
    r.p[3] = (__builtin_bit_cast(f16x2, t3) - zz) * ss;
    return r.v;
}

// ========= pre-pass: x fp32 -> f16, fragment-major 128-row tiles =========
// x16 layout: [mt(64)][kt(64)][fk(8)][row(128)][octet(8)], octet = pairs
// (e, e+4) of k = kt*64 + fk*8 + e. Serves 32x32 fragment reads via
// fk = ks2*2 + half.
__global__ __launch_bounds__(256)
void prep_kernel(const float* __restrict__ x, _Float16* __restrict__ x16) {
    const int b  = blockIdx.x;          // mt*64 + kt
    const int mt = b >> 6, kt = b & 63;
    _Float16* dst = x16 + (size_t)b * TILE_ELEMS;
#pragma unroll
    for (int it = 0; it < 4; ++it) {
        const int o   = it * 256 + threadIdx.x;   // 0..1023 = fk*128 + row
        const int fk  = o >> 7, row = o & 127;
        const float* src = x + (size_t)(mt * 128 + row) * K_DIM + kt * 64 + fk * 8;
        f32x4 a0 = *(const f32x4*)src;
        f32x4 a1 = *(const f32x4*)(src + 4);
        H8 v;
#pragma unroll
        for (int j = 0; j < 4; ++j)
            v.p[j] = __builtin_bit_cast(f16x2, __builtin_amdgcn_cvt_pkrtz(a0[j], a1[j]));
        *(f16x8*)(dst + (size_t)o * 8) = v.v;
    }
}

// Counted-vmcnt no-drain barrier (T4, R17-proven): wait until <=N VMEM
// outstanding; the N newest (B/sz loads) stay in flight across the barrier.
#define BARC(N) do {                                                         \
    __builtin_amdgcn_sched_barrier(0);                                       \
    asm volatile("s_waitcnt vmcnt(" #N ") lgkmcnt(0)" ::: "memory");         \
    __builtin_amdgcn_s_barrier();                                            \
    __builtin_amdgcn_sched_barrier(0);                                       \
} while (0)

// ===== 128x128 tile, 4 waves in N (wave-tile 128x32, acc=4x f32x16=64),
// ===== 32x32x16 MFMA: one qweight word = one B-fragment (col=lane&31,
// ===== k=(lane>>5)*8+j). A via global_load_lds DMA dbuf + T4 barriers.
// R18 bug fixed: B packed-row base is `half`, not `2*half` (rows needed are
// kt*8 + ks2*2 + half; half=1 lanes were reading even rows = wrong k's).
__global__ __launch_bounds__(256, 4)
void qgemm_dma_kernel(const _Float16* __restrict__ x16, const uint32_t* __restrict__ qw,
                      const uint32_t* __restrict__ qz, const float* __restrict__ sc,
                      const float* __restrict__ bias, float* __restrict__ out)
{
    __shared__ _Float16 As[2 * TILE_ELEMS];   // 2 x 16 KiB, fragment-major, linear

    const int tid  = threadIdx.x;
    const int lid  = (blockIdx.x & 7) * (NWG / 8) + (blockIdx.x >> 3); // XCD swizzle
    const int mt   = lid / NXT;
    const int n0   = (lid % NXT) * BN;

    const int lane  = tid & 63, wid = tid >> 6;  // wid 0..3 = N slot (32 cols)
    const int col32 = lane & 31;                 // fragment column
    const int half  = lane >> 5;                 // k-half (8 k's each)

    f32x16 acc[4];
#pragma unroll
    for (int i = 0; i < 4; ++i) {
        f32x16 z = {0.f,0.f,0.f,0.f,0.f,0.f,0.f,0.f,
                    0.f,0.f,0.f,0.f,0.f,0.f,0.f,0.f};
        acc[i] = z;
    }

    uint32_t breg[2][4];              // [set][ks2] — one word = one B-frag
    f16x2    ssv, zzv;
    float    s_nxt;
    uint32_t z_nxt;

    const int colg = n0 + wid * 32 + col32;   // this lane's single column
    const int shz  = 4 * (lane & 7);          // qzeros nibble shift (col&7)

    const _Float16* xsrc = x16 + (size_t)mt * (64 * TILE_ELEMS) + tid * 8;
    const uint32_t* qpB  = qw + (size_t)half * N_DIM + colg;  // row = kt*8 + ks2*2 + half

// 256 threads x 4 DMAs x 16 B = 16 KiB tile (linear dst, per intrinsic contract)
#define STAGE(BUF, KT) do {                                                  \
    const _Float16* s_ = xsrc + (size_t)(KT) * TILE_ELEMS;                   \
    _Float16* d_ = &As[(BUF) * TILE_ELEMS + tid * 8];                        \
    _Pragma("unroll") for (int it = 0; it < 4; ++it)                         \
        __builtin_amdgcn_global_load_lds(                                    \
            (const __attribute__((address_space(1))) void*)(s_ + it * 2048), \
            (__attribute__((address_space(3))) void*)(d_ + it * 2048), 16, 0, 0); \
    __builtin_amdgcn_sched_barrier(0);  /* pin: DMAs oldest in vmcnt queue */ \
    } while (0)

// B word for k-slice ks2: packed row = kt*8 + ks2*2 + half (base holds half)
#define LOADB(SET) do {                                                      \
    breg[SET][0] = qpB[0];                                                   \
    breg[SET][1] = qpB[(size_t)2 * N_DIM];                                   \
    breg[SET][2] = qpB[(size_t)4 * N_DIM];                                   \
    breg[SET][3] = qpB[(size_t)6 * N_DIM];                                   \
    qpB += (size_t)8 * N_DIM; } while (0)

#define LOADSZ(G) do {                                                       \
    s_nxt = sc[(size_t)(G) * N_DIM + colg];                                  \
    z_nxt = qz[(size_t)(G) * NZW + (colg >> 3)]; } while (0)

#define MAKESZ() do {                                                        \
    _Float16 zh = (_Float16)(float)(1024u + ((z_nxt >> shz) & 15u));         \
    _Float16 sh = (_Float16)s_nxt;                                           \
    f16x2 sp = {sh, sh}; ssv = sp;                                           \
    f16x2 zp = {zh, zh}; zzv = zp; } while (0)

// 4 k-slices x 4 M-tiles; A-frag read: fk = ks2*2+half, row = mti*32+col32.
// 32 lanes read 32 consecutive 16B slots; halves differ by +2048B -> 2-way
// bank aliasing = free (m136).
#define COMPUTE(BUF, SET) do {                                               \
    _Pragma("unroll") for (int ks2 = 0; ks2 < 4; ++ks2) {                    \
        f16x8 bf_ = dq_word(breg[SET][ks2], ssv, zzv);                       \
        const int fo_ = (BUF) * TILE_ELEMS + (ks2 * 2 + half) * 1024 + col32 * 8; \
        _Pragma("unroll") for (int mti = 0; mti < 4; ++mti) {                \
            f16x8 af_ = *(const f16x8*)&As[fo_ + mti * 256];                 \
            acc[mti] = __builtin_amdgcn_mfma_f32_32x32x16_f16(af_, bf_, acc[mti], 0, 0, 0); \
        } } } while (0)

    // -------- prologue: s/z(g0) oldest, tile0 DMA, B(0); wait DMAs only --------
    LOADSZ(0);          // 2 loads (oldest — MAKESZ waits only these)
    STAGE(0, 0);        // 4 DMAs
    LOADB(0);           // 4 loads (stay outstanding through barrier)
    MAKESZ();           // consumes oldest 2 -> cheap vmcnt(8)
    BARC(4);            // tile-0 DMA landed; B(0) in flight

    for (int kt2 = 0; kt2 < NT / 2; ++kt2) {
        const int t0 = 2 * kt2;
        // ---- even tile t0 (buf0, set0); DMA t0+1 -> buf1 ----
        STAGE(1, t0 + 1);       // DMAs oldest (macro pins with sched_barrier)
        LOADB(1);               // B(t0+1): crosses the barrier
        COMPUTE(0, 0);
        BARC(4);                // wait buf1 DMAs only

        // ---- odd tile t0+1 (buf1, set1); DMA t0+2 -> buf0 ----
        if (kt2 + 1 < NT / 2) {
            STAGE(0, t0 + 2);
            LOADB(0);
            LOADSZ(kt2 + 1);    // next group's raw s/z
            COMPUTE(1, 1);      // group kt2 (GROUP=128 = 2 K-tiles)
            MAKESZ();           // group kt2+1 (s/z landed during COMPUTE)
            BARC(6);            // wait buf0 DMAs; B(t0+2) crosses barrier
        } else {
            COMPUTE(1, 1);      // final tile; epilogue doesn't touch LDS
        }
    }

#undef STAGE
#undef LOADB
#undef LOADSZ
#undef MAKESZ
#undef COMPUTE

    // epilogue: 32x32 C/D layout (m74/m101): col = lane&31,
    // row = (reg&3) + 8*(reg>>2) + 4*(lane>>5)
    const float bj = bias[colg];
    const int m0 = mt * BM;
#pragma unroll
    for (int mti = 0; mti < 4; ++mti) {
        const int rbase = m0 + mti * 32 + 4 * half;
#pragma unroll
        for (int reg = 0; reg < 16; ++reg) {
            const int row = rbase + (reg & 3) + 8 * (reg >> 2);
            out[(size_t)row * N_DIM + colg] = acc[mti][reg] + bj;
        }
    }
}

// ================= fallback (R14 kernel, 910 µs proven) for small ws =================
constexpr int FB_LDA = 64;

#define BAR() do {                                           \
    asm volatile("s_waitcnt lgkmcnt(0)" ::: "memory");       \
    __builtin_amdgcn_s_barrier();                            \
    __builtin_amdgcn_sched_barrier(0);                       \
} while (0)

__global__ __launch_bounds__(256, 3)
void qgemm_fb_kernel(const float* __restrict__ x, const uint32_t* __restrict__ qw,
                     const uint32_t* __restrict__ qz, const float* __restrict__ sc,
                     const float* __restrict__ bias, float* __restrict__ out)
{
    __shared__ _Float16 As[2][BM * FB_LDA];

    const int tid  = threadIdx.x;
    const int lid  = (blockIdx.x & 7) * (NWG / 8) + (blockIdx.x >> 3);
    const int m0   = (lid / NXT) * BM;
    const int n0   = (lid % NXT) * BN;

    const int lane = tid & 63, wid = tid >> 6;
    const int lr = lane & 15, lk = lane >> 4;
    const int sw = lr & 7;

    const int arow = tid >> 3;
    const int acp  = tid & 7;
    const int wslot = acp ^ (arow & 7);

    f32x4 acc[8][2];
#pragma unroll
    for (int i = 0; i < 8; ++i)
#pragma unroll
        for (int j = 0; j < 2; ++j) { f32x4 z = {0.f,0.f,0.f,0.f}; acc[i][j] = z; }

    f32x4    aS[4][2];
    uint32_t breg[2][4];
    f16x2    ssv[2], zzv[2];
    float    s_nxt[2];
    uint32_t z_nxt[2];

    const int ncb = n0 + wid * 32 + lr;
    const int shz = 4 * (lr & 7);
    const float* xbase = x + (size_t)(m0 + arow) * K_DIM + acp * 8;

    const uint32_t* qp0 = qw + (size_t)lk * N_DIM + ncb;
    const uint32_t* qp1 = qp0 + (size_t)4 * N_DIM;

#define A_LOAD(KT) do { const float* ap_ = xbase + (KT) * BK;                \
    _Pragma("unroll") for (int i = 0; i < 4; ++i) {                          \
        const float* src_ = ap_ + (size_t)(i * 32) * K_DIM;                  \
        aS[i][0] = *(const f32x4*)(src_);                                    \
        aS[i][1] = *(const f32x4*)(src_ + 4); } } while (0)

#define A_WRITE(BUF) do {                                                    \
    _Pragma("unroll") for (int i = 0; i < 4; ++i) { H8 v_;                   \
        _Pragma("unroll") for (int j = 0; j < 4; ++j)                        \
            v_.p[j] = __builtin_bit_cast(f16x2,                              \
                __builtin_amdgcn_cvt_pkrtz(aS[i][0][j], aS[i][1][j]));       \
        *(f16x8*)&As[BUF][(arow + i * 32) * FB_LDA + wslot * 8] = v_.v; } } while (0)

#define LOADB(SET) do {                                                      \
    breg[SET][0] = qp0[0];  breg[SET][1] = qp0[16];                          \
    breg[SET][2] = qp1[0];  breg[SET][3] = qp1[16];                          \
    qp0 += (size_t)8 * N_DIM; qp1 += (size_t)8 * N_DIM; } while (0)

#define LOADSZ(G) do { _Pragma("unroll") for (int j = 0; j < 2; ++j) {       \
    s_nxt[j] = sc[(size_t)(G) * N_DIM + ncb + j * 16];                       \
    z_nxt[j] = qz[(size_t)(G) * NZW + (ncb >> 3) + j * 2]; } } while (0)

#define MAKESZ() do { _Pragma("unroll") for (int j = 0; j < 2; ++j) {        \
    _Float16 zh = (_Float16)(float)(1024u + ((z_nxt[j] >> shz) & 15u));      \
    _Float16 sh = (_Float16)s_nxt[j];                                        \
    f16x2 sp = {sh, sh}; ssv[j] = sp;                                        \
    f16x2 zp = {zh, zh}; zzv[j] = zp; } } while (0)

#define COMPUTE(BUF, SET) do {                                               \
    _Pragma("unroll") for (int ks = 0; ks < 2; ++ks) {                       \
        f16x8 bf0 = dq_word(breg[SET][ks * 2],     ssv[0], zzv[0]);          \
        f16x8 bf1 = dq_word(breg[SET][ks * 2 + 1], ssv[1], zzv[1]);          \
        const int rs_ = ((ks * 4 + lk) ^ sw) * 8;                            \
        _Pragma("unroll") for (int i = 0; i < 8; ++i) {                      \
            f16x8 af_ = *(const f16x8*)&As[BUF][(i * 16 + lr) * FB_LDA + rs_]; \
            acc[i][0] = __builtin_amdgcn_mfma_f32_16x16x32_f16(af_, bf0, acc[i][0], 0, 0, 0); \
            acc[i][1] = __builtin_amdgcn_mfma_f32_16x16x32_f16(af_, bf1, acc[i][1], 0, 0, 0); \
        } } } while (0)

    LOADSZ(0);
    A_LOAD(0);
    LOADB(0);
    A_WRITE(0);
    BAR();

    for (int kt2 = 0; kt2 < NT / 2; ++kt2) {
        const int t0 = 2 * kt2;
        MAKESZ();
        A_LOAD(t0 + 1);
        LOADB(1);
        COMPUTE(0, 0);
        A_WRITE(1);
        BAR();

        if (kt2 + 1 < NT / 2) {
            A_LOAD(t0 + 2);
            LOADB(0);
            LOADSZ(kt2 + 1);
            COMPUTE(1, 1);
            A_WRITE(0);
        } else {
            COMPUTE(1, 1);
        }
        BAR();
    }

#undef A_LOAD
#undef A_WRITE
#undef LOADB
#undef LOADSZ
#undef MAKESZ
#undef COMPUTE

    const int ccol0 = n0 + wid * 32 + lr;
    float bj[2];
#pragma unroll
    for (int j = 0; j < 2; ++j) bj[j] = bias[ccol0 + j * 16];
#pragma unroll
    for (int i = 0; i < 8; ++i) {
        const int rbase = m0 + i * 16 + lk * 4;
#pragma unroll
        for (int j = 0; j < 2; ++j) {
            const int col = ccol0 + j * 16;
#pragma unroll
            for (int r = 0; r < 4; ++r)
                out[(size_t)(rbase + r) * N_DIM + col] = acc[i][j][r] + bj[j];
        }
    }
}

extern "C" void kernel_launch(void* const* d_in, const int* in_sizes, int n_in,
                              void* d_out, int out_size, void* d_ws, size_t ws_size,
                              hipStream_t stream) {
    const float*    xp = (const float*)d_in[0];
    const uint32_t* qw = (const uint32_t*)d_in[1];
    const uint32_t* qz = (const uint32_t*)d_in[2];
    const float*    sc = (const float*)d_in[3];
    const float*    bi = (const float*)d_in[4];
    float*          op = (float*)d_out;
    (void)in_sizes; (void)n_in; (void)out_size;

    const size_t need = (size_t)M_DIM * K_DIM * sizeof(_Float16); // 64 MiB
    if (ws_size >= need) {
        prep_kernel<<<dim3(MXT * NT), dim3(256), 0, stream>>>(xp, (_Float16*)d_ws);
        qgemm_dma_kernel<<<dim3(NWG), dim3(256), 0, stream>>>((const _Float16*)d_ws, qw, qz, sc, bi, op);
    } else {
        qgemm_fb_kernel<<<dim3(NWG), dim3(256), 0, stream>>>(xp, qw, qz, sc, bi, op);
    }
}

// Round 20
// 962.397 us; speedup vs baseline: 4.4021x; 4.4021x over previous
//
#include <hip/hip_runtime.h>
#include <stdint.h>

#define K_DIM 4096
#define N_DIM 11008
#define M_DIM 8192

constexpr int BM = 128, BN = 128, BK = 64;
constexpr int NT  = K_DIM / BK;    // 64
constexpr int NZW = N_DIM / 8;     // 1376
constexpr int NXT = N_DIM / BN;    // 86
constexpr int MXT = M_DIM / BM;    // 64
constexpr int NWG = NXT * MXT;     // 5504 = 8 * 688
constexpr int TILE_ELEMS = BM * BK;  // 8192 f16 = 16 KiB per K-tile

typedef _Float16 f16x2  __attribute__((ext_vector_type(2)));
typedef _Float16 f16x8  __attribute__((ext_vector_type(8)));
typedef float    f32x4  __attribute__((ext_vector_type(4)));
typedef float    f32x16 __attribute__((ext_vector_type(16)));
union H8 { f16x8 v; f16x2 p[4]; };

// word w holds nibbles for k-offsets 0..7; output k-order (0,4,1,5,2,6,3,7).
// Legal for MFMA because A octets carry the SAME permutation (via prep):
// element j of A and B refer to the same true k, so the 8-k sum is complete.
__device__ __forceinline__ f16x8 dq_word(uint32_t w, f16x2 ss, f16x2 zz) {
    H8 r;
    uint32_t t0 = ( w        & 0x000F000Fu) | 0x64006400u;
    uint32_t t1 = ((w >> 4)  & 0x000F000Fu) | 0x64006400u;
    uint32_t t2 = ((w >> 8)  & 0x000F000Fu) | 0x64006400u;
    uint32_t t3 = ((w >> 12) & 0x000F000Fu) | 0x64006400u;
    r.p[0] = (__builtin_bit_cast(f16x2, t0) - zz) * ss;
    r.p[1] = (__builtin_bit_cast(f16x2, t1) - zz) * ss;
    r.p[2] = (__builtin_bit_cast(f16x2, t2) - zz) * ss;
    r.p[3] = (__builtin_bit_cast(f16x2, t3) - zz) * ss;
    return r.v;
}

// ========= pre-pass: x fp32 -> f16, fragment-major 128-row tiles =========
// x16 layout: [mt(64)][kt(64)][fk(8)][row(128)][octet(8)], octet = pairs
// (e, e+4) of k = kt*64 + fk*8 + e. 32x32 fragment reads: fk = ks2*2 + half.
__global__ __launch_bounds__(256)
void prep_kernel(const float* __restrict__ x, _Float16* __restrict__ x16) {
    const int b  = blockIdx.x;          // mt*64 + kt
    const int mt = b >> 6, kt = b & 63;
    _Float16* dst = x16 + (size_t)b * TILE_ELEMS;
#pragma unroll
    for (int it = 0; it < 4; ++it) {
        const int o   = it * 256 + threadIdx.x;   // 0..1023 = fk*128 + row
        const int fk  = o >> 7, row = o & 127;
        const float* src = x + (size_t)(mt * 128 + row) * K_DIM + kt * 64 + fk * 8;
        f32x4 a0 = *(const f32x4*)src;
        f32x4 a1 = *(const f32x4*)(src + 4);
        H8 v;
#pragma unroll
        for (int j = 0; j < 4; ++j)
            v.p[j] = __builtin_bit_cast(f16x2, __builtin_amdgcn_cvt_pkrtz(a0[j], a1[j]));
        *(f16x8*)(dst + (size_t)o * 8) = v.v;
    }
}

// Counted-vmcnt no-drain barrier (T4, R17-proven): wait until <=N VMEM
// outstanding; the N newest (B/sz loads) stay in flight across the barrier.
#define BARC(N) do {                                                         \
    __builtin_amdgcn_sched_barrier(0);                                       \
    asm volatile("s_waitcnt vmcnt(" #N ") lgkmcnt(0)" ::: "memory");         \
    __builtin_amdgcn_s_barrier();                                            \
    __builtin_amdgcn_sched_barrier(0);                                       \
} while (0)

// ===== 128x128 tile, 4 waves in N (wave-tile 128x32, acc=4x f32x16=64),
// ===== 32x32x16 MFMA. (256,3): budget ~170 regs/wave — acc(64, 16-aligned
// ===== AGPR tuples) + ~100 VGPR working set fits. (256,4)'s 128-cap spilled
// ===== 12.8 GB/dispatch in R19 (same failure mode as R9/R16).
__global__ __launch_bounds__(256, 3)
void qgemm_dma_kernel(const _Float16* __restrict__ x16, const uint32_t* __restrict__ qw,
                      const uint32_t* __restrict__ qz, const float* __restrict__ sc,
                      const float* __restrict__ bias, float* __restrict__ out)
{
    __shared__ _Float16 As[2 * TILE_ELEMS];   // 2 x 16 KiB, fragment-major, linear

    const int tid  = threadIdx.x;
    const int lid  = (blockIdx.x & 7) * (NWG / 8) + (blockIdx.x >> 3); // XCD swizzle
    const int mt   = lid / NXT;
    const int n0   = (lid % NXT) * BN;

    const int lane  = tid & 63, wid = tid >> 6;  // wid 0..3 = N slot (32 cols)
    const int col32 = lane & 31;                 // fragment column
    const int half  = lane >> 5;                 // k-half (8 k's each)

    f32x16 acc[4];
#pragma unroll
    for (int i = 0; i < 4; ++i) {
        f32x16 z = {0.f,0.f,0.f,0.f,0.f,0.f,0.f,0.f,
                    0.f,0.f,0.f,0.f,0.f,0.f,0.f,0.f};
        acc[i] = z;
    }

    uint32_t breg[2][4];              // [set][ks2] — one word = one B-frag
    f16x2    ssv, zzv;
    float    s_nxt;
    uint32_t z_nxt;

    const int colg = n0 + wid * 32 + col32;   // this lane's single column
    const int shz  = 4 * (lane & 7);          // qzeros nibble shift (col&7)

    const _Float16* xsrc = x16 + (size_t)mt * (64 * TILE_ELEMS) + tid * 8;
    const uint32_t* qpB  = qw + (size_t)half * N_DIM + colg;  // row = kt*8 + ks2*2 + half

// 256 threads x 4 DMAs x 16 B = 16 KiB tile (linear dst, per intrinsic contract)
#define STAGE(BUF, KT) do {                                                  \
    const _Float16* s_ = xsrc + (size_t)(KT) * TILE_ELEMS;                   \
    _Float16* d_ = &As[(BUF) * TILE_ELEMS + tid * 8];                        \
    _Pragma("unroll") for (int it = 0; it < 4; ++it)                         \
        __builtin_amdgcn_global_load_lds(                                    \
            (const __attribute__((address_space(1))) void*)(s_ + it * 2048), \
            (__attribute__((address_space(3))) void*)(d_ + it * 2048), 16, 0, 0); \
    __builtin_amdgcn_sched_barrier(0);  /* pin: DMAs oldest in vmcnt queue */ \
    } while (0)

// B word for k-slice ks2: packed row = kt*8 + ks2*2 + half (base holds half)
#define LOADB(SET) do {                                                      \
    breg[SET][0] = qpB[0];                                                   \
    breg[SET][1] = qpB[(size_t)2 * N_DIM];                                   \
    breg[SET][2] = qpB[(size_t)4 * N_DIM];                                   \
    breg[SET][3] = qpB[(size_t)6 * N_DIM];                                   \
    qpB += (size_t)8 * N_DIM; } while (0)

#define LOADSZ(G) do {                                                       \
    s_nxt = sc[(size_t)(G) * N_DIM + colg];                                  \
    z_nxt = qz[(size_t)(G) * NZW + (colg >> 3)]; } while (0)

#define MAKESZ() do {                                                        \
    _Float16 zh = (_Float16)(float)(1024u + ((z_nxt >> shz) & 15u));         \
    _Float16 sh = (_Float16)s_nxt;                                           \
    f16x2 sp = {sh, sh}; ssv = sp;                                           \
    f16x2 zp = {zh, zh}; zzv = zp; } while (0)

// 4 k-slices x 4 M-tiles; A-frag read: fk = ks2*2+half, row = mti*32+col32.
// 32 lanes read 32 consecutive 16B slots; halves differ by +2048B -> 2-way
// bank aliasing = free (m136).
#define COMPUTE(BUF, SET) do {                                               \
    _Pragma("unroll") for (int ks2 = 0; ks2 < 4; ++ks2) {                    \
        f16x8 bf_ = dq_word(breg[SET][ks2], ssv, zzv);                       \
        const int fo_ = (BUF) * TILE_ELEMS + (ks2 * 2 + half) * 1024 + col32 * 8; \
        _Pragma("unroll") for (int mti = 0; mti < 4; ++mti) {                \
            f16x8 af_ = *(const f16x8*)&As[fo_ + mti * 256];                 \
            acc[mti] = __builtin_amdgcn_mfma_f32_32x32x16_f16(af_, bf_, acc[mti], 0, 0, 0); \
        } } } while (0)

    // -------- prologue: s/z(g0) oldest, tile0 DMA, B(0); wait DMAs only --------
    LOADSZ(0);          // 2 loads (oldest — MAKESZ waits only these)
    STAGE(0, 0);        // 4 DMAs
    LOADB(0);           // 4 loads (stay outstanding through barrier)
    MAKESZ();           // consumes oldest 2 -> cheap vmcnt wait
    BARC(4);            // tile-0 DMA landed; B(0) in flight

    for (int kt2 = 0; kt2 < NT / 2; ++kt2) {
        const int t0 = 2 * kt2;
        // ---- even tile t0 (buf0, set0); DMA t0+1 -> buf1 ----
        STAGE(1, t0 + 1);       // DMAs oldest (macro pins with sched_barrier)
        LOADB(1);               // B(t0+1): crosses the barrier
        COMPUTE(0, 0);
        BARC(4);                // wait buf1 DMAs only

        // ---- odd tile t0+1 (buf1, set1); DMA t0+2 -> buf0 ----
        if (kt2 + 1 < NT / 2) {
            STAGE(0, t0 + 2);
            LOADB(0);
            LOADSZ(kt2 + 1);    // next group's raw s/z
            COMPUTE(1, 1);      // group kt2 (GROUP=128 = 2 K-tiles)
            MAKESZ();           // group kt2+1 (s/z landed during COMPUTE)
            BARC(6);            // wait buf0 DMAs; B(t0+2) crosses barrier
        } else {
            COMPUTE(1, 1);      // final tile; epilogue doesn't touch LDS
        }
    }

#undef STAGE
#undef LOADB
#undef LOADSZ
#undef MAKESZ
#undef COMPUTE

    // epilogue: 32x32 C/D layout (m74/m101): col = lane&31,
    // row = (reg&3) + 8*(reg>>2) + 4*(lane>>5)
    const float bj = bias[colg];
    const int m0 = mt * BM;
#pragma unroll
    for (int mti = 0; mti < 4; ++mti) {
        const int rbase = m0 + mti * 32 + 4 * half;
#pragma unroll
        for (int reg = 0; reg < 16; ++reg) {
            const int row = rbase + (reg & 3) + 8 * (reg >> 2);
            out[(size_t)row * N_DIM + colg] = acc[mti][reg] + bj;
        }
    }
}

// ================= fallback (R14 kernel, 910 µs proven) for small ws =================
constexpr int FB_LDA = 64;

#define BAR() do {                                           \
    asm volatile("s_waitcnt lgkmcnt(0)" ::: "memory");       \
    __builtin_amdgcn_s_barrier();                            \
    __builtin_amdgcn_sched_barrier(0);                       \
} while (0)

__global__ __launch_bounds__(256, 3)
void qgemm_fb_kernel(const float* __restrict__ x, const uint32_t* __restrict__ qw,
                     const uint32_t* __restrict__ qz, const float* __restrict__ sc,
                     const float* __restrict__ bias, float* __restrict__ out)
{
    __shared__ _Float16 As[2][BM * FB_LDA];

    const int tid  = threadIdx.x;
    const int lid  = (blockIdx.x & 7) * (NWG / 8) + (blockIdx.x >> 3);
    const int m0   = (lid / NXT) * BM;
    const int n0   = (lid % NXT) * BN;

    const int lane = tid & 63, wid = tid >> 6;
    const int lr = lane & 15, lk = lane >> 4;
    const int sw = lr & 7;

    const int arow = tid >> 3;
    const int acp  = tid & 7;
    const int wslot = acp ^ (arow & 7);

    f32x4 acc[8][2];
#pragma unroll
    for (int i = 0; i < 8; ++i)
#pragma unroll
        for (int j = 0; j < 2; ++j) { f32x4 z = {0.f,0.f,0.f,0.f}; acc[i][j] = z; }

    f32x4    aS[4][2];
    uint32_t breg[2][4];
    f16x2    ssv[2], zzv[2];
    float    s_nxt[2];
    uint32_t z_nxt[2];

    const int ncb = n0 + wid * 32 + lr;
    const int shz = 4 * (lr & 7);
    const float* xbase = x + (size_t)(m0 + arow) * K_DIM + acp * 8;

    const uint32_t* qp0 = qw + (size_t)lk * N_DIM + ncb;
    const uint32_t* qp1 = qp0 + (size_t)4 * N_DIM;

#define A_LOAD(KT) do { const float* ap_ = xbase + (KT) * BK;                \
    _Pragma("unroll") for (int i = 0; i < 4; ++i) {                          \
        const float* src_ = ap_ + (size_t)(i * 32) * K_DIM;                  \
        aS[i][0] = *(const f32x4*)(src_);                                    \
        aS[i][1] = *(const f32x4*)(src_ + 4); } } while (0)

#define A_WRITE(BUF) do {                                                    \
    _Pragma("unroll") for (int i = 0; i < 4; ++i) { H8 v_;                   \
        _Pragma("unroll") for (int j = 0; j < 4; ++j)                        \
            v_.p[j] = __builtin_bit_cast(f16x2,                              \
                __builtin_amdgcn_cvt_pkrtz(aS[i][0][j], aS[i][1][j]));       \
        *(f16x8*)&As[BUF][(arow + i * 32) * FB_LDA + wslot * 8] = v_.v; } } while (0)

#define LOADB(SET) do {                                                      \
    breg[SET][0] = qp0[0];  breg[SET][1] = qp0[16];                          \
    breg[SET][2] = qp1[0];  breg[SET][3] = qp1[16];                          \
    qp0 += (size_t)8 * N_DIM; qp1 += (size_t)8 * N_DIM; } while (0)

#define LOADSZ(G) do { _Pragma("unroll") for (int j = 0; j < 2; ++j) {       \
    s_nxt[j] = sc[(size_t)(G) * N_DIM + ncb + j * 16];                       \
    z_nxt[j] = qz[(size_t)(G) * NZW + (ncb >> 3) + j * 2]; } } while (0)

#define MAKESZ() do { _Pragma("unroll") for (int j = 0; j < 2; ++j) {        \
    _Float16 zh = (_Float16)(float)(1024u + ((z_nxt[j] >> shz) & 15u));      \
    _Float16 sh = (_Float16)s_nxt[j];                                        \
    f16x2 sp = {sh, sh}; ssv[j] = sp;                                        \
    f16x2 zp = {zh, zh}; zzv[j] = zp; } } while (0)

#define COMPUTE(BUF, SET) do {                                               \
    _Pragma("unroll") for (int ks = 0; ks < 2; ++ks) {                       \
        f16x8 bf0 = dq_word(breg[SET][ks * 2],     ssv[0], zzv[0]);          \
        f16x8 bf1 = dq_word(breg[SET][ks * 2 + 1], ssv[1], zzv[1]);          \
        const int rs_ = ((ks * 4 + lk) ^ sw) * 8;                            \
        _Pragma("unroll") for (int i = 0; i < 8; ++i) {                      \
            f16x8 af_ = *(const f16x8*)&As[BUF][(i * 16 + lr) * FB_LDA + rs_]; \
            acc[i][0] = __builtin_amdgcn_mfma_f32_16x16x32_f16(af_, bf0, acc[i][0], 0, 0, 0); \
            acc[i][1] = __builtin_amdgcn_mfma_f32_16x16x32_f16(af_, bf1, acc[i][1], 0, 0, 0); \
        } } } while (0)

    LOADSZ(0);
    A_LOAD(0);
    LOADB(0);
    A_WRITE(0);
    BAR();

    for (int kt2 = 0; kt2 < NT / 2; ++kt2) {
        const int t0 = 2 * kt2;
        MAKESZ();
        A_LOAD(t0 + 1);
        LOADB(1);
        COMPUTE(0, 0);
        A_WRITE(1);
        BAR();

        if (kt2 + 1 < NT / 2) {
            A_LOAD(t0 + 2);
            LOADB(0);
            LOADSZ(kt2 + 1);
            COMPUTE(1, 1);
            A_WRITE(0);
        } else {
            COMPUTE(1, 1);
        }
        BAR();
    }

#undef A_LOAD
#undef A_WRITE
#undef LOADB
#undef LOADSZ
#undef MAKESZ
#undef COMPUTE

    const int ccol0 = n0 + wid * 32 + lr;
    float bj[2];
#pragma unroll
    for (int j = 0; j < 2; ++j) bj[j] = bias[ccol0 + j * 16];
#pragma unroll
    for (int i = 0; i < 8; ++i) {
        const int rbase = m0 + i * 16 + lk * 4;
#pragma unroll
        for (int j = 0; j < 2; ++j) {
            const int col = ccol0 + j * 16;
#pragma unroll
            for (int r = 0; r < 4; ++r)
                out[(size_t)(rbase + r) * N_DIM + col] = acc[i][j][r] + bj[j];
        }
    }
}

extern "C" void kernel_launch(void* const* d_in, const int* in_sizes, int n_in,
                              void* d_out, int out_size, void* d_ws, size_t ws_size,
                              hipStream_t stream) {
    const float*    xp = (const float*)d_in[0];
    const uint32_t* qw = (const uint32_t*)d_in[1];
    const uint32_t* qz = (const uint32_t*)d_in[2];
    const float*    sc = (const float*)d_in[3];
    const float*    bi = (const float*)d_in[4];
    float*          op = (float*)d_out;
    (void)in_sizes; (void)n_in; (void)out_size;

    const size_t need = (size_t)M_DIM * K_DIM * sizeof(_Float16); // 64 MiB
    if (ws_size >= need) {
        prep_kernel<<<dim3(MXT * NT), dim3(256), 0, stream>>>(xp, (_Float16*)d_ws);
        qgemm_dma_kernel<<<dim3(NWG), dim3(256), 0, stream>>>((const _Float16*)d_ws, qw, qz, sc, bi, op);
    } else {
        qgemm_fb_kernel<<<dim3(NWG), dim3(256), 0, stream>>>(xp, qw, qz, sc, bi, op);
    }
}

// Round 21
// 723.321 us; speedup vs baseline: 5.8571x; 1.3305x over previous
//
#include <hip/hip_runtime.h>
#include <stdint.h>

#define K_DIM 4096
#define N_DIM 11008
#define M_DIM 8192

constexpr int BM = 128, BN = 128, BK = 64;
constexpr int NT  = K_DIM / BK;    // 64
constexpr int NZW = N_DIM / 8;     // 1376
constexpr int NXT = N_DIM / BN;    // 86
constexpr int MXT = M_DIM / BM;    // 64
constexpr int NWG = NXT * MXT;     // 5504 = 8 * 688
constexpr int TILE_ELEMS = BM * BK;  // 8192 f16 = 16 KiB per K-tile

typedef _Float16 f16x2 __attribute__((ext_vector_type(2)));
typedef _Float16 f16x8 __attribute__((ext_vector_type(8)));
typedef float    f32x4 __attribute__((ext_vector_type(4)));
union H8 { f16x8 v; f16x2 p[4]; };

// word w holds nibbles for k-offsets 0..7; output k-order (0,4,1,5,2,6,3,7).
// Exact: (1024+q) - (1024+z) is Sterbenz-exact; single rounding on *s.
__device__ __forceinline__ f16x8 dq_word(uint32_t w, f16x2 ss, f16x2 zz) {
    H8 r;
    uint32_t t0 = ( w        & 0x000F000Fu) | 0x64006400u;
    uint32_t t1 = ((w >> 4)  & 0x000F000Fu) | 0x64006400u;
    uint32_t t2 = ((w >> 8)  & 0x000F000Fu) | 0x64006400u;
    uint32_t t3 = ((w >> 12) & 0x000F000Fu) | 0x64006400u;
    r.p[0] = (__builtin_bit_cast(f16x2, t0) - zz) * ss;
    r.p[1] = (__builtin_bit_cast(f16x2, t1) - zz) * ss;
    r.p[2] = (__builtin_bit_cast(f16x2, t2) - zz) * ss;
    r.p[3] = (__builtin_bit_cast(f16x2, t3) - zz) * ss;
    return r.v;
}

// ========= pre-pass: x fp32 -> f16, fragment-major 128-row tiles =========
// x16 layout: [mt(64)][kt(64)][fk(8)][row(128)][octet(8)], octet = pairs
// (e, e+4) of k = kt*64 + fk*8 + e  (matches dq_word's output permutation).
__global__ __launch_bounds__(256)
void prep_kernel(const float* __restrict__ x, _Float16* __restrict__ x16) {
    const int b  = blockIdx.x;          // mt*64 + kt
    const int mt = b >> 6, kt = b & 63;
    _Float16* dst = x16 + (size_t)b * TILE_ELEMS;
#pragma unroll
    for (int it = 0; it < 4; ++it) {
        const int o   = it * 256 + threadIdx.x;   // 0..1023 = fk*128 + row
        const int fk  = o >> 7, row = o & 127;
        const float* src = x + (size_t)(mt * 128 + row) * K_DIM + kt * 64 + fk * 8;
        f32x4 a0 = *(const f32x4*)src;
        f32x4 a1 = *(const f32x4*)(src + 4);
        H8 v;
#pragma unroll
        for (int j = 0; j < 4; ++j)
            v.p[j] = __builtin_bit_cast(f16x2, __builtin_amdgcn_cvt_pkrtz(a0[j], a1[j]));
        *(f16x8*)(dst + (size_t)o * 8) = v.v;
    }
}

// Counted-vmcnt no-drain barrier (T4, R17-proven): wait until <=N VMEM
// outstanding; the N newest (B/sz loads) stay in flight across the barrier.
#define BARC(N) do {                                                         \
    __builtin_amdgcn_sched_barrier(0);                                       \
    asm volatile("s_waitcnt vmcnt(" #N ") lgkmcnt(0)" ::: "memory");         \
    __builtin_amdgcn_s_barrier();                                            \
    __builtin_amdgcn_sched_barrier(0);                                       \
} while (0)

// ===== R17 kernel (734 µs proven) + T5 s_setprio around the MFMA cluster =====
// 128x128 tile, 4 waves in N (wave-tile 128x32, acc=64), 16x16x32 MFMA,
// A via global_load_lds DMA dbuf, counted-vmcnt barriers.
__global__ __launch_bounds__(256, 4)
void qgemm_dma_kernel(const _Float16* __restrict__ x16, const uint32_t* __restrict__ qw,
                      const uint32_t* __restrict__ qz, const float* __restrict__ sc,
                      const float* __restrict__ bias, float* __restrict__ out)
{
    __shared__ _Float16 As[2 * TILE_ELEMS];   // 2 x 16 KiB, fragment-major, linear

    const int tid  = threadIdx.x;
    const int lid  = (blockIdx.x & 7) * (NWG / 8) + (blockIdx.x >> 3); // XCD swizzle
    const int mt   = lid / NXT;
    const int n0   = (lid % NXT) * BN;

    const int lane = tid & 63, wid = tid >> 6;   // wid 0..3 = N slot
    const int lr = lane & 15, lk = lane >> 4;

    f32x4 acc[8][2];
#pragma unroll
    for (int i = 0; i < 8; ++i)
#pragma unroll
        for (int j = 0; j < 2; ++j) {
            f32x4 z = {0.f, 0.f, 0.f, 0.f};
            acc[i][j] = z;
        }

    uint32_t breg[2][4];              // [set][ks*2+j]
    f16x2    ssv[2], zzv[2];
    float    s_nxt[2];
    uint32_t z_nxt[2];

    const int ncb = n0 + wid * 32 + lr;   // lane's base col; covers ncb, ncb+16
    const int shz = 4 * (lr & 7);

    const _Float16* xsrc = x16 + (size_t)mt * (64 * TILE_ELEMS) + tid * 8;
    const uint32_t* qp0 = qw + (size_t)lk * N_DIM + ncb;   // ks=0 word row
    const uint32_t* qp1 = qp0 + (size_t)4 * N_DIM;         // ks=1 word row

// 256 threads x 4 DMAs x 16 B = 16 KiB tile (linear dst, per intrinsic contract)
#define STAGE(BUF, KT) do {                                                  \
    const _Float16* s_ = xsrc + (size_t)(KT) * TILE_ELEMS;                   \
    _Float16* d_ = &As[(BUF) * TILE_ELEMS + tid * 8];                        \
    _Pragma("unroll") for (int it = 0; it < 4; ++it)                         \
        __builtin_amdgcn_global_load_lds(                                    \
            (const __attribute__((address_space(1))) void*)(s_ + it * 2048), \
            (__attribute__((address_space(3))) void*)(d_ + it * 2048), 16, 0, 0); \
    __builtin_amdgcn_sched_barrier(0);  /* pin: DMAs oldest in vmcnt queue */ \
    } while (0)

#define LOADB(SET) do {                                                      \
    breg[SET][0] = qp0[0];  breg[SET][1] = qp0[16];                          \
    breg[SET][2] = qp1[0];  breg[SET][3] = qp1[16];                          \
    qp0 += (size_t)8 * N_DIM; qp1 += (size_t)8 * N_DIM; } while (0)

#define LOADSZ(G) do { _Pragma("unroll") for (int j = 0; j < 2; ++j) {       \
    s_nxt[j] = sc[(size_t)(G) * N_DIM + ncb + j * 16];                       \
    z_nxt[j] = qz[(size_t)(G) * NZW + (ncb >> 3) + j * 2]; } } while (0)

#define MAKESZ() do { _Pragma("unroll") for (int j = 0; j < 2; ++j) {        \
    _Float16 zh = (_Float16)(float)(1024u + ((z_nxt[j] >> shz) & 15u));      \
    _Float16 sh = (_Float16)s_nxt[j];                                        \
    f16x2 sp = {sh, sh}; ssv[j] = sp;                                        \
    f16x2 zp = {zh, zh}; zzv[j] = zp; } } while (0)

// wave spans ALL 128 rows (i=0..7), 32 cols (j=0..1). Fragment-major reads:
// 16-lane beat = 256 B contiguous -> conflict-free (R15/R17: conflicts = 0).
// T5: setprio(1) around the MFMA cluster — with 3-4 independent blocks/CU at
// different phases, the CU scheduler can favor MFMA-issuing waves (attn-like
// regime, m191 +4-7%), unlike m190's single-block lockstep null.
#define COMPUTE(BUF, SET) do {                                               \
    _Pragma("unroll") for (int ks = 0; ks < 2; ++ks) {                       \
        f16x8 bf0 = dq_word(breg[SET][ks * 2],     ssv[0], zzv[0]);          \
        f16x8 bf1 = dq_word(breg[SET][ks * 2 + 1], ssv[1], zzv[1]);          \
        const int fo_ = (BUF) * TILE_ELEMS + (ks * 4 + lk) * 1024 + lr * 8;  \
        __builtin_amdgcn_s_setprio(1);                                       \
        _Pragma("unroll") for (int i = 0; i < 8; ++i) {                      \
            f16x8 af_ = *(const f16x8*)&As[fo_ + i * 128];                   \
            acc[i][0] = __builtin_amdgcn_mfma_f32_16x16x32_f16(af_, bf0, acc[i][0], 0, 0, 0); \
            acc[i][1] = __builtin_amdgcn_mfma_f32_16x16x32_f16(af_, bf1, acc[i][1], 0, 0, 0); \
        }                                                                    \
        __builtin_amdgcn_s_setprio(0);                                       \
    } } while (0)

    // -------- prologue: s/z(g0) oldest, tile0 DMA, B(0); wait DMAs only --------
    LOADSZ(0);          // 4 loads (oldest; retired by BARC(4))
    STAGE(0, 0);        // 4 DMAs
    LOADB(0);           // 4 loads (stay outstanding through barrier)
    BARC(4);            // tile-0 DMA landed; B(0) in flight

    for (int kt2 = 0; kt2 < NT / 2; ++kt2) {
        const int t0 = 2 * kt2;
        // ---- even tile t0 (buf0, set0); DMA t0+1 -> buf1 ----
        MAKESZ();               // group kt2: s/z loaded >=1 phase ago (landed)
        STAGE(1, t0 + 1);       // DMAs oldest (macro pins with sched_barrier)
        LOADB(1);               // B(t0+1): stays in flight across barrier
        COMPUTE(0, 0);
        BARC(4);                // wait buf1 DMAs only; B loads cross the barrier

        // ---- odd tile t0+1 (buf1, set1); DMA t0+2 -> buf0 ----
        if (kt2 + 1 < NT / 2) {
            STAGE(0, t0 + 2);
            LOADB(0);
            LOADSZ(kt2 + 1);    // next group's raw s/z (consumed 2 phases later)
            COMPUTE(1, 1);      // group kt2 (GROUP=128 = 2 K-tiles)
            BARC(8);            // wait buf0 DMAs; B + s/z loads cross barrier
        } else {
            COMPUTE(1, 1);      // final tile; epilogue doesn't touch LDS
        }
    }

#undef STAGE
#undef LOADB
#undef LOADSZ
#undef MAKESZ
#undef COMPUTE

    // epilogue: C/D layout col = lane&15, row = (lane>>4)*4 + reg
    const int ccol0 = n0 + wid * 32 + lr;
    float bj[2];
#pragma unroll
    for (int j = 0; j < 2; ++j) bj[j] = bias[ccol0 + j * 16];
    const int m0 = mt * BM;
#pragma unroll
    for (int i = 0; i < 8; ++i) {
        const int rbase = m0 + i * 16 + lk * 4;
#pragma unroll
        for (int j = 0; j < 2; ++j) {
            const int col = ccol0 + j * 16;
#pragma unroll
            for (int r = 0; r < 4; ++r)
                out[(size_t)(rbase + r) * N_DIM + col] = acc[i][j][r] + bj[j];
        }
    }
}

// ================= fallback (R14 kernel, 910 µs proven) for small ws =================
constexpr int FB_LDA = 64;

#define BAR() do {                                           \
    asm volatile("s_waitcnt lgkmcnt(0)" ::: "memory");       \
    __builtin_amdgcn_s_barrier();                            \
    __builtin_amdgcn_sched_barrier(0);                       \
} while (0)

__global__ __launch_bounds__(256, 3)
void qgemm_fb_kernel(const float* __restrict__ x, const uint32_t* __restrict__ qw,
                     const uint32_t* __restrict__ qz, const float* __restrict__ sc,
                     const float* __restrict__ bias, float* __restrict__ out)
{
    __shared__ _Float16 As[2][BM * FB_LDA];

    const int tid  = threadIdx.x;
    const int lid  = (blockIdx.x & 7) * (NWG / 8) + (blockIdx.x >> 3);
    const int m0   = (lid / NXT) * BM;
    const int n0   = (lid % NXT) * BN;

    const int lane = tid & 63, wid = tid >> 6;
    const int lr = lane & 15, lk = lane >> 4;
    const int sw = lr & 7;

    const int arow = tid >> 3;
    const int acp  = tid & 7;
    const int wslot = acp ^ (arow & 7);

    f32x4 acc[8][2];
#pragma unroll
    for (int i = 0; i < 8; ++i)
#pragma unroll
        for (int j = 0; j < 2; ++j) { f32x4 z = {0.f,0.f,0.f,0.f}; acc[i][j] = z; }

    f32x4    aS[4][2];
    uint32_t breg[2][4];
    f16x2    ssv[2], zzv[2];
    float    s_nxt[2];
    uint32_t z_nxt[2];

    const int ncb = n0 + wid * 32 + lr;
    const int shz = 4 * (lr & 7);
    const float* xbase = x + (size_t)(m0 + arow) * K_DIM + acp * 8;

    const uint32_t* qp0 = qw + (size_t)lk * N_DIM + ncb;
    const uint32_t* qp1 = qp0 + (size_t)4 * N_DIM;

#define A_LOAD(KT) do { const float* ap_ = xbase + (KT) * BK;                \
    _Pragma("unroll") for (int i = 0; i < 4; ++i) {                          \
        const float* src_ = ap_ + (size_t)(i * 32) * K_DIM;                  \
        aS[i][0] = *(const f32x4*)(src_);                                    \
        aS[i][1] = *(const f32x4*)(src_ + 4); } } while (0)

#define A_WRITE(BUF) do {                                                    \
    _Pragma("unroll") for (int i = 0; i < 4; ++i) { H8 v_;                   \
        _Pragma("unroll") for (int j = 0; j < 4; ++j)                        \
            v_.p[j] = __builtin_bit_cast(f16x2,                              \
                __builtin_amdgcn_cvt_pkrtz(aS[i][0][j], aS[i][1][j]));       \
        *(f16x8*)&As[BUF][(arow + i * 32) * FB_LDA + wslot * 8] = v_.v; } } while (0)

#define LOADB(SET) do {                                                      \
    breg[SET][0] = qp0[0];  breg[SET][1] = qp0[16];                          \
    breg[SET][2] = qp1[0];  breg[SET][3] = qp1[16];                          \
    qp0 += (size_t)8 * N_DIM; qp1 += (size_t)8 * N_DIM; } while (0)

#define LOADSZ(G) do { _Pragma("unroll") for (int j = 0; j < 2; ++j) {       \
    s_nxt[j] = sc[(size_t)(G) * N_DIM + ncb + j * 16];                       \
    z_nxt[j] = qz[(size_t)(G) * NZW + (ncb >> 3) + j * 2]; } } while (0)

#define MAKESZ() do { _Pragma("unroll") for (int j = 0; j < 2; ++j) {        \
    _Float16 zh = (_Float16)(float)(1024u + ((z_nxt[j] >> shz) & 15u));      \
    _Float16 sh = (_Float16)s_nxt[j];                                        \
    f16x2 sp = {sh, sh}; ssv[j] = sp;                                        \
    f16x2 zp = {zh, zh}; zzv[j] = zp; } } while (0)

#define COMPUTE(BUF, SET) do {                                               \
    _Pragma("unroll") for (int ks = 0; ks < 2; ++ks) {                       \
        f16x8 bf0 = dq_word(breg[SET][ks * 2],     ssv[0], zzv[0]);          \
        f16x8 bf1 = dq_word(breg[SET][ks * 2 + 1], ssv[1], zzv[1]);          \
        const int rs_ = ((ks * 4 + lk) ^ sw) * 8;                            \
        _Pragma("unroll") for (int i = 0; i < 8; ++i) {                      \
            f16x8 af_ = *(const f16x8*)&As[BUF][(i * 16 + lr) * FB_LDA + rs_]; \
            acc[i][0] = __builtin_amdgcn_mfma_f32_16x16x32_f16(af_, bf0, acc[i][0], 0, 0, 0); \
            acc[i][1] = __builtin_amdgcn_mfma_f32_16x16x32_f16(af_, bf1, acc[i][1], 0, 0, 0); \
        } } } while (0)

    LOADSZ(0);
    A_LOAD(0);
    LOADB(0);
    A_WRITE(0);
    BAR();

    for (int kt2 = 0; kt2 < NT / 2; ++kt2) {
        const int t0 = 2 * kt2;
        MAKESZ();
        A_LOAD(t0 + 1);
        LOADB(1);
        COMPUTE(0, 0);
        A_WRITE(1);
        BAR();

        if (kt2 + 1 < NT / 2) {
            A_LOAD(t0 + 2);
            LOADB(0);
            LOADSZ(kt2 + 1);
            COMPUTE(1, 1);
            A_WRITE(0);
        } else {
            COMPUTE(1, 1);
        }
        BAR();
    }

#undef A_LOAD
#undef A_WRITE
#undef LOADB
#undef LOADSZ
#undef MAKESZ
#undef COMPUTE

    const int ccol0 = n0 + wid * 32 + lr;
    float bj[2];
#pragma unroll
    for (int j = 0; j < 2; ++j) bj[j] = bias[ccol0 + j * 16];
#pragma unroll
    for (int i = 0; i < 8; ++i) {
        const int rbase = m0 + i * 16 + lk * 4;
#pragma unroll
        for (int j = 0; j < 2; ++j) {
            const int col = ccol0 + j * 16;
#pragma unroll
            for (int r = 0; r < 4; ++r)
                out[(size_t)(rbase + r) * N_DIM + col] = acc[i][j][r] + bj[j];
        }
    }
}

extern "C" void kernel_launch(void* const* d_in, const int* in_sizes, int n_in,
                              void* d_out, int out_size, void* d_ws, size_t ws_size,
                              hipStream_t stream) {
    const float*    xp = (const float*)d_in[0];
    const uint32_t* qw = (const uint32_t*)d_in[1];
    const uint32_t* qz = (const uint32_t*)d_in[2];
    const float*    sc = (const float*)d_in[3];
    const float*    bi = (const float*)d_in[4];
    float*          op = (float*)d_out;
    (void)in_sizes; (void)n_in; (void)out_size;

    const size_t need = (size_t)M_DIM * K_DIM * sizeof(_Float16); // 64 MiB
    if (ws_size >= need) {
        prep_kernel<<<dim3(MXT * NT), dim3(256), 0, stream>>>(xp, (_Float16*)d_ws);
        qgemm_dma_kernel<<<dim3(NWG), dim3(256), 0, stream>>>((const _Float16*)d_ws, qw, qz, sc, bi, op);
    } else {
        qgemm_fb_kernel<<<dim3(NWG), dim3(256), 0, stream>>>(xp, qw, qz, sc, bi, op);
    }
}